// Round 1
// baseline (2273.826 us; speedup 1.0000x reference)
//
#include <hip/hip_runtime.h>
#include <math.h>

#define HWn 16384
#define Hn  128
#define Wn  128
#define Bn  2
#define Cn  96
#define En  192
#define Gn  24
#define HEADn 16
#define CCn 12
#define Nn  12
#define HDn 384

// ---------------------------------------------------------------------------
// K1: channel LayerNorm (eps 1e-6) + grouped 1x1 in-projection.
// grid (128, 2): x = pixel tiles over B*L, y = stream (0 rgb, 1 e)
// one thread = one pixel; 96 channels held in registers (fully unrolled).
// ---------------------------------------------------------------------------
__global__ __launch_bounds__(256) void k_ln_inproj(
    const float* __restrict__ x0, const float* __restrict__ x1,
    const float* __restrict__ lw0, const float* __restrict__ lb0,
    const float* __restrict__ lw1, const float* __restrict__ lb1,
    const float* __restrict__ pw0, const float* __restrict__ pw1,
    float* __restrict__ xr, float* __restrict__ v)
{
  const int s  = blockIdx.y;
  const int gp = blockIdx.x * 256 + threadIdx.x;   // 0..B*L-1
  const int b  = gp >> 14, l = gp & (HWn - 1);
  const float* x  = s ? x1  : x0;
  const float* lw = s ? lw1 : lw0;
  const float* lb = s ? lb1 : lb0;
  const float* pw = s ? pw1 : pw0;

  float xv[Cn];
  float sum = 0.f, ss = 0.f;
  const float* xp = x + (size_t)b * Cn * HWn + l;
#pragma unroll
  for (int ch = 0; ch < Cn; ++ch) {
    float t = xp[(size_t)ch * HWn];
    xv[ch] = t; sum += t; ss += t * t;
  }
  float mu  = sum * (1.f / Cn);
  float var = ss * (1.f / Cn) - mu * mu;
  float rs  = rsqrtf(var + 1e-6f);

  float* xrp = xr + ((size_t)s * Bn + b) * Cn * HWn + l;
#pragma unroll
  for (int ch = 0; ch < Cn; ++ch) {
    float n = fmaf((xv[ch] - mu) * rs, lw[ch], lb[ch]);
    xv[ch] = n;
    xrp[(size_t)ch * HWn] = n;
  }

  float* vp = v + ((size_t)s * Bn + b) * En * HWn + l;
#pragma unroll
  for (int g = 0; g < Gn; ++g) {
#pragma unroll
    for (int o = 0; o < 8; ++o) {
      float a = 0.f;
#pragma unroll
      for (int i = 0; i < 4; ++i) a = fmaf(xv[g * 4 + i], pw[g * 32 + o * 4 + i], a);
      vp[(size_t)(g * 8 + o) * HWn] = a;
    }
  }
}

// ---------------------------------------------------------------------------
// K2: depthwise 3x3 conv (cross-correlation, SAME, zero pad) + bias + SiLU.
// grid (64, 192, 4): x = pixel tiles, y = channel e, z = s*2+b
// ---------------------------------------------------------------------------
__global__ __launch_bounds__(256) void k_dwconv_silu(
    const float* __restrict__ v,
    const float* __restrict__ cw0, const float* __restrict__ cb0,
    const float* __restrict__ cw1, const float* __restrict__ cb1,
    float* __restrict__ u)
{
  const int z = blockIdx.z;                 // s*2+b
  const int e = blockIdx.y;
  const int p = blockIdx.x * 256 + threadIdx.x;
  const int h = p >> 7, w = p & 127;
  const int s = z >> 1;
  const float* cw  = (s ? cw1 : cw0) + e * 9;
  const float bias = (s ? cb1 : cb0)[e];
  const float* src = v + ((size_t)z * En + e) * HWn;

  float acc = bias;
#pragma unroll
  for (int kh = 0; kh < 3; ++kh) {
    int hh = h + kh - 1;
    if (hh < 0 || hh >= Hn) continue;
#pragma unroll
    for (int kw = 0; kw < 3; ++kw) {
      int ww = w + kw - 1;
      if (ww < 0 || ww >= Wn) continue;
      acc = fmaf(src[hh * Wn + ww], cw[kh * 3 + kw], acc);
    }
  }
  float sig = 1.f / (1.f + expf(-acc));
  u[((size_t)z * En + e) * HWn + p] = acc * sig;
}

// ---------------------------------------------------------------------------
// K3: SSM core. 16 pixels per block of 512 threads.
//  phase0: stage u (both streams) into LDS
//  phase1: x_dbl[s][r][cc] = sum_d u[s][d*12+cc] * xproj_w[s][r][d]
//  phase2: per-thread (px, s, d): dt = softplus(dts*dtw+dtb); 12-step scan
//          over cc with state h[12]; C taken from the OTHER stream (cross).
//          y += u*Ds; LayerNorm over cc (eps 1e-5); yn -> LDS (reuse uS)
//  phase3: grouped 1x1 outproj (24 x (4x8)) + residual xr -> z
// ---------------------------------------------------------------------------
__global__ __launch_bounds__(512) void k_ssm(
    const float* __restrict__ u_ws, const float* __restrict__ xr_ws,
    float* __restrict__ z_ws,
    const float* __restrict__ xprojw, const float* __restrict__ dtprojw,
    const float* __restrict__ dtprojb, const float* __restrict__ A_logs,
    const float* __restrict__ Ds,
    const float* __restrict__ on1w, const float* __restrict__ on1b,
    const float* __restrict__ on2w, const float* __restrict__ on2b,
    const float* __restrict__ opw0, const float* __restrict__ opw1)
{
  __shared__ float uS[2 * En * 16];        // 6144 f, also reused for yn
  __shared__ float xdl[2 * 25 * CCn * 16]; // 9600 f
  const int tid  = threadIdx.x;
  const int tile = blockIdx.x;
  const int b  = (tile * 16) >> 14;
  const int l0 = (tile * 16) & (HWn - 1);

  // phase 0: 6144 = 12*512 loads
#pragma unroll
  for (int i = 0; i < 12; ++i) {
    int idx = i * 512 + tid;
    int px = idx & 15, ch = (idx >> 4) % En, s2 = idx / (En * 16);
    uS[(s2 * En + ch) * 16 + px] =
        u_ws[(((size_t)s2 * Bn + b) * En + ch) * HWn + l0 + px];
  }
  __syncthreads();

  // phase 1: 9600 outputs
  for (int j = 0; j < 19; ++j) {
    int idx = j * 512 + tid;
    if (idx < 9600) {
      int px = idx & 15, cc = (idx >> 4) % 12, r = (idx / 192) % 25, s2 = idx / 4800;
      const float* xw = xprojw + (s2 * 25 + r) * HEADn;
      float a = 0.f;
#pragma unroll
      for (int d = 0; d < HEADn; ++d)
        a = fmaf(uS[(s2 * En + d * 12 + cc) * 16 + px], xw[d], a);
      xdl[((s2 * 25 + r) * 12 + cc) * 16 + px] = a;
    }
  }
  __syncthreads();

  // phase 2: scan. thread = (px, s, d)
  const int px = tid >> 5, s = (tid >> 4) & 1, d = tid & 15;
  const float dtw = dtprojw[s * HEADn + d];
  const float dtb = dtprojb[s * HEADn + d];
  const float Dv  = Ds[s * HEADn + d];
  float Ar[Nn];
#pragma unroll
  for (int n = 0; n < Nn; ++n) Ar[n] = -expf(A_logs[(s * HEADn + d) * Nn + n]);
  float hst[Nn];
#pragma unroll
  for (int n = 0; n < Nn; ++n) hst[n] = 0.f;
  float yv[CCn];
#pragma unroll
  for (int cc = 0; cc < CCn; ++cc) {
    float dts = xdl[(s * 25 * 12 + cc) * 16 + px];            // r = 0
    float pre = fmaf(dts, dtw, dtb);
    float dt_s = (pre > 20.f) ? pre : log1pf(expf(pre));      // softplus
    float u_s  = uS[(s * En + d * 12 + cc) * 16 + px];
    float dtu  = dt_s * u_s;
    float ya = 0.f;
#pragma unroll
    for (int n = 0; n < Nn; ++n) {
      float dA = expf(dt_s * Ar[n]);
      hst[n] = fmaf(dA, hst[n], dtu * xdl[((s * 25 + 1 + n) * 12 + cc) * 16 + px]);
      ya = fmaf(hst[n], xdl[(((1 - s) * 25 + 13 + n) * 12 + cc) * 16 + px], ya);
    }
    yv[cc] = fmaf(u_s, Dv, ya);
  }

  // LayerNorm over cc, eps 1e-5
  float mu = 0.f;
#pragma unroll
  for (int cc = 0; cc < CCn; ++cc) mu += yv[cc];
  mu *= (1.f / CCn);
  float var = 0.f;
#pragma unroll
  for (int cc = 0; cc < CCn; ++cc) { float t = yv[cc] - mu; var = fmaf(t, t, var); }
  var *= (1.f / CCn);
  float rs = rsqrtf(var + 1e-5f);
  const float* ow = s ? on2w : on1w;
  const float* ob = s ? on2b : on1b;
  __syncthreads();                      // everyone done reading uS
#pragma unroll
  for (int cc = 0; cc < CCn; ++cc)
    uS[(s * En + d * 12 + cc) * 16 + px] = fmaf((yv[cc] - mu) * rs, ow[cc], ob[cc]);
  __syncthreads();

  // phase 3: outproj (192 -> 96 grouped) + residual. 3072 = 6*512 outputs
#pragma unroll
  for (int j = 0; j < 6; ++j) {
    int idx = j * 512 + tid;
    int pxx = idx & 15, ch = (idx >> 4) % 96, ss = idx / 1536;
    int g = ch >> 2, co = ch & 3;
    const float* ow2 = (ss ? opw1 : opw0) + g * 32 + co * 8;
    float a = 0.f;
#pragma unroll
    for (int ci = 0; ci < 8; ++ci)
      a = fmaf(uS[(ss * En + g * 8 + ci) * 16 + pxx], ow2[ci], a);
    a += xr_ws[(((size_t)ss * Bn + b) * Cn + ch) * HWn + l0 + pxx];
    z_ws[(((size_t)ss * Bn + b) * Cn + ch) * HWn + l0 + pxx] = a;
  }
}

// ---------------------------------------------------------------------------
// K4a: chan LN (eps 1e-6) + fc1 (384x96) + bias + exact GELU -> t
// one thread = one pixel (per stream launch)
// ---------------------------------------------------------------------------
__global__ __launch_bounds__(256) void k_mlp_fc1(
    const float* __restrict__ z, const float* __restrict__ nw, const float* __restrict__ nb,
    const float* __restrict__ w1, const float* __restrict__ b1,
    float* __restrict__ t)
{
  const int gp = blockIdx.x * 256 + threadIdx.x;
  const int b = gp >> 14, l = gp & (HWn - 1);
  const float* zp = z + (size_t)b * Cn * HWn + l;
  float zn[Cn];
  float sum = 0.f, ss = 0.f;
#pragma unroll
  for (int c = 0; c < Cn; ++c) { float x = zp[(size_t)c * HWn]; zn[c] = x; sum += x; ss += x * x; }
  float mu = sum * (1.f / Cn), var = ss * (1.f / Cn) - mu * mu, rs = rsqrtf(var + 1e-6f);
#pragma unroll
  for (int c = 0; c < Cn; ++c) zn[c] = fmaf((zn[c] - mu) * rs, nw[c], nb[c]);

  float* tp = t + (size_t)b * HDn * HWn + l;
  for (int o = 0; o < HDn; ++o) {
    const float* wr = w1 + o * Cn;       // wave-uniform -> scalar loads
    float a = b1[o];
#pragma unroll
    for (int c = 0; c < Cn; ++c) a = fmaf(zn[c], wr[c], a);
    float ge = 0.5f * a * (1.f + erff(a * 0.70710678118654752f));
    tp[(size_t)o * HWn] = ge;
  }
}

// K4b: fc2 (96x384, pre-transposed weights) + bias + residual -> out
__global__ __launch_bounds__(256) void k_mlp_fc2(
    const float* __restrict__ t, const float* __restrict__ z,
    const float* __restrict__ w2t, const float* __restrict__ b2,
    float* __restrict__ out)
{
  const int gp = blockIdx.x * 256 + threadIdx.x;
  const int b = gp >> 14, l = gp & (HWn - 1);
  const float* tp = t + (size_t)b * HDn * HWn + l;
  float acc[Cn];
#pragma unroll
  for (int c = 0; c < Cn; ++c) acc[c] = 0.f;
  for (int o = 0; o < HDn; ++o) {
    float g = tp[(size_t)o * HWn];
    const float* wr = w2t + o * Cn;      // wave-uniform -> scalar loads
#pragma unroll
    for (int c = 0; c < Cn; ++c) acc[c] = fmaf(g, wr[c], acc[c]);
  }
  const float* zp = z + (size_t)b * Cn * HWn + l;
  float* op = out + (size_t)b * Cn * HWn + l;
#pragma unroll
  for (int c = 0; c < Cn; ++c)
    op[(size_t)c * HWn] = acc[c] + b2[c] + zp[(size_t)c * HWn];
}

__global__ void k_transpose_w2(const float* __restrict__ w2, float* __restrict__ w2t)
{
  int idx = blockIdx.x * 256 + threadIdx.x;     // idx = o*96 + c
  if (idx < Cn * HDn) {
    int c = idx % Cn, o = idx / Cn;
    w2t[idx] = w2[c * HDn + o];
  }
}

// ---------------------------------------------------------------------------
extern "C" void kernel_launch(void* const* d_in, const int* in_sizes, int n_in,
                              void* d_out, int out_size, void* d_ws, size_t ws_size,
                              hipStream_t stream)
{
  const float* x_rgb = (const float*)d_in[0];
  const float* x_e   = (const float*)d_in[1];
  const float* in1_w = (const float*)d_in[2];
  const float* in1_b = (const float*)d_in[3];
  const float* in2_w = (const float*)d_in[4];
  const float* in2_b = (const float*)d_in[5];
  const float* ipw0  = (const float*)d_in[6];
  const float* ipw1  = (const float*)d_in[7];
  const float* cw0   = (const float*)d_in[8];
  const float* cb0   = (const float*)d_in[9];
  const float* cw1   = (const float*)d_in[10];
  const float* cb1   = (const float*)d_in[11];
  const float* xprojw  = (const float*)d_in[12];
  const float* dtprojw = (const float*)d_in[13];
  const float* dtprojb = (const float*)d_in[14];
  const float* A_logs  = (const float*)d_in[15];
  const float* Ds      = (const float*)d_in[16];
  const float* on1w  = (const float*)d_in[17];
  const float* on1b  = (const float*)d_in[18];
  const float* on2w  = (const float*)d_in[19];
  const float* on2b  = (const float*)d_in[20];
  const float* opw0  = (const float*)d_in[21];
  const float* opw1  = (const float*)d_in[22];
  const float* n1w   = (const float*)d_in[23];
  const float* n1b   = (const float*)d_in[24];
  const float* n2w   = (const float*)d_in[25];
  const float* n2b   = (const float*)d_in[26];
  const float* w1r   = (const float*)d_in[27];
  const float* b1r   = (const float*)d_in[28];
  const float* w2r   = (const float*)d_in[29];
  const float* b2r   = (const float*)d_in[30];
  const float* w1e   = (const float*)d_in[31];
  const float* b1e   = (const float*)d_in[32];
  const float* w2e   = (const float*)d_in[33];
  const float* b2e   = (const float*)d_in[34];

  float* ws  = (float*)d_ws;
  float* xr  = ws;                                   // 2*B*C*HW  = 6291456 f
  float* vz  = ws + (size_t)6291456;                 // 2*B*E*HW  = 12582912 f (v, later z)
  float* ut  = ws + (size_t)6291456 + 12582912;      // 12582912 f (u, later t per-stream)
  float* w2t = ws + (size_t)31457280;                // 36864 f

  dim3 b256(256);

  k_ln_inproj<<<dim3(128, 2), b256, 0, stream>>>(
      x_rgb, x_e, in1_w, in1_b, in2_w, in2_b, ipw0, ipw1, xr, vz);

  k_dwconv_silu<<<dim3(64, En, 4), b256, 0, stream>>>(
      vz, cw0, cb0, cw1, cb1, ut);

  k_ssm<<<dim3(2048), dim3(512), 0, stream>>>(
      ut, xr, vz, xprojw, dtprojw, dtprojb, A_logs, Ds,
      on1w, on1b, on2w, on2b, opw0, opw1);

  for (int s = 0; s < 2; ++s) {
    const float* zs  = vz + (size_t)s * Bn * Cn * HWn;
    float* outs = (float*)d_out + (size_t)s * Bn * Cn * HWn;
    k_mlp_fc1<<<dim3(128), b256, 0, stream>>>(
        zs, s ? n2w : n1w, s ? n2b : n1b, s ? w1e : w1r, s ? b1e : b1r, ut);
    k_transpose_w2<<<dim3(144), b256, 0, stream>>>(s ? w2e : w2r, w2t);
    k_mlp_fc2<<<dim3(128), b256, 0, stream>>>(
        ut, zs, w2t, s ? b2e : b2r, outs);
  }
}

// Round 3
// 780.687 us; speedup vs baseline: 2.9126x; 2.9126x over previous
//
#include <hip/hip_runtime.h>
#include <math.h>

#define HWn 16384
#define Hn  128
#define Wn  128
#define Bn  2
#define Cn  96
#define En  192
#define Gn  24
#define HEADn 16
#define CCn 12
#define Nn  12
#define HDn 384

// ---------------------------------------------------------------------------
// K1: channel LayerNorm (eps 1e-6) + grouped 1x1 in-projection.
// grid (128, 2): x = pixel tiles over B*L, y = stream (0 rgb, 1 e)
// ---------------------------------------------------------------------------
__global__ __launch_bounds__(256) void k_ln_inproj(
    const float* __restrict__ x0, const float* __restrict__ x1,
    const float* __restrict__ lw0, const float* __restrict__ lb0,
    const float* __restrict__ lw1, const float* __restrict__ lb1,
    const float* __restrict__ pw0, const float* __restrict__ pw1,
    float* __restrict__ xr, float* __restrict__ v)
{
  const int s  = blockIdx.y;
  const int gp = blockIdx.x * 256 + threadIdx.x;   // 0..B*L-1
  const int b  = gp >> 14, l = gp & (HWn - 1);
  const float* x  = s ? x1  : x0;
  const float* lw = s ? lw1 : lw0;
  const float* lb = s ? lb1 : lb0;
  const float* pw = s ? pw1 : pw0;

  float xv[Cn];
  float sum = 0.f, ss = 0.f;
  const float* xp = x + (size_t)b * Cn * HWn + l;
#pragma unroll
  for (int ch = 0; ch < Cn; ++ch) {
    float t = xp[(size_t)ch * HWn];
    xv[ch] = t; sum += t; ss += t * t;
  }
  float mu  = sum * (1.f / Cn);
  float var = ss * (1.f / Cn) - mu * mu;
  float rs  = rsqrtf(var + 1e-6f);

  float* xrp = xr + ((size_t)s * Bn + b) * Cn * HWn + l;
#pragma unroll
  for (int ch = 0; ch < Cn; ++ch) {
    float n = fmaf((xv[ch] - mu) * rs, lw[ch], lb[ch]);
    xv[ch] = n;
    xrp[(size_t)ch * HWn] = n;
  }

  float* vp = v + ((size_t)s * Bn + b) * En * HWn + l;
#pragma unroll
  for (int g = 0; g < Gn; ++g) {
#pragma unroll
    for (int o = 0; o < 8; ++o) {
      float a = 0.f;
#pragma unroll
      for (int i = 0; i < 4; ++i) a = fmaf(xv[g * 4 + i], pw[g * 32 + o * 4 + i], a);
      vp[(size_t)(g * 8 + o) * HWn] = a;
    }
  }
}

// ---------------------------------------------------------------------------
// K2: depthwise 3x3 conv + bias + SiLU. grid (64, 192, 4)
// ---------------------------------------------------------------------------
__global__ __launch_bounds__(256) void k_dwconv_silu(
    const float* __restrict__ v,
    const float* __restrict__ cw0, const float* __restrict__ cb0,
    const float* __restrict__ cw1, const float* __restrict__ cb1,
    float* __restrict__ u)
{
  const int z = blockIdx.z;                 // s*2+b
  const int e = blockIdx.y;
  const int p = blockIdx.x * 256 + threadIdx.x;
  const int h = p >> 7, w = p & 127;
  const int s = z >> 1;
  const float* cw  = (s ? cw1 : cw0) + e * 9;
  const float bias = (s ? cb1 : cb0)[e];
  const float* src = v + ((size_t)z * En + e) * HWn;

  float acc = bias;
#pragma unroll
  for (int kh = 0; kh < 3; ++kh) {
    int hh = h + kh - 1;
    if (hh < 0 || hh >= Hn) continue;
#pragma unroll
    for (int kw = 0; kw < 3; ++kw) {
      int ww = w + kw - 1;
      if (ww < 0 || ww >= Wn) continue;
      acc = fmaf(src[hh * Wn + ww], cw[kh * 3 + kw], acc);
    }
  }
  float sig = 1.f / (1.f + expf(-acc));
  u[((size_t)z * En + e) * HWn + p] = acc * sig;
}

// ---------------------------------------------------------------------------
// K3: SSM core. 16 pixels per block of 512 threads.
// ---------------------------------------------------------------------------
__global__ __launch_bounds__(512) void k_ssm(
    const float* __restrict__ u_ws, const float* __restrict__ xr_ws,
    float* __restrict__ z_ws,
    const float* __restrict__ xprojw, const float* __restrict__ dtprojw,
    const float* __restrict__ dtprojb, const float* __restrict__ A_logs,
    const float* __restrict__ Ds,
    const float* __restrict__ on1w, const float* __restrict__ on1b,
    const float* __restrict__ on2w, const float* __restrict__ on2b,
    const float* __restrict__ opw0, const float* __restrict__ opw1)
{
  __shared__ float uS[2 * En * 16];        // 6144 f, also reused for yn
  __shared__ float xdl[2 * 25 * CCn * 16]; // 9600 f
  const int tid  = threadIdx.x;
  const int tile = blockIdx.x;
  const int b  = (tile * 16) >> 14;
  const int l0 = (tile * 16) & (HWn - 1);

#pragma unroll
  for (int i = 0; i < 12; ++i) {
    int idx = i * 512 + tid;
    int px = idx & 15, ch = (idx >> 4) % En, s2 = idx / (En * 16);
    uS[(s2 * En + ch) * 16 + px] =
        u_ws[(((size_t)s2 * Bn + b) * En + ch) * HWn + l0 + px];
  }
  __syncthreads();

  for (int j = 0; j < 19; ++j) {
    int idx = j * 512 + tid;
    if (idx < 9600) {
      int px = idx & 15, cc = (idx >> 4) % 12, r = (idx / 192) % 25, s2 = idx / 4800;
      const float* xw = xprojw + (s2 * 25 + r) * HEADn;
      float a = 0.f;
#pragma unroll
      for (int d = 0; d < HEADn; ++d)
        a = fmaf(uS[(s2 * En + d * 12 + cc) * 16 + px], xw[d], a);
      xdl[((s2 * 25 + r) * 12 + cc) * 16 + px] = a;
    }
  }
  __syncthreads();

  const int px = tid >> 5, s = (tid >> 4) & 1, d = tid & 15;
  const float dtw = dtprojw[s * HEADn + d];
  const float dtb = dtprojb[s * HEADn + d];
  const float Dv  = Ds[s * HEADn + d];
  float Ar[Nn];
#pragma unroll
  for (int n = 0; n < Nn; ++n) Ar[n] = -expf(A_logs[(s * HEADn + d) * Nn + n]);
  float hst[Nn];
#pragma unroll
  for (int n = 0; n < Nn; ++n) hst[n] = 0.f;
  float yv[CCn];
#pragma unroll
  for (int cc = 0; cc < CCn; ++cc) {
    float dts = xdl[(s * 25 * 12 + cc) * 16 + px];            // r = 0
    float pre = fmaf(dts, dtw, dtb);
    float dt_s = (pre > 20.f) ? pre : log1pf(expf(pre));      // softplus
    float u_s  = uS[(s * En + d * 12 + cc) * 16 + px];
    float dtu  = dt_s * u_s;
    float ya = 0.f;
#pragma unroll
    for (int n = 0; n < Nn; ++n) {
      float dA = expf(dt_s * Ar[n]);
      hst[n] = fmaf(dA, hst[n], dtu * xdl[((s * 25 + 1 + n) * 12 + cc) * 16 + px]);
      ya = fmaf(hst[n], xdl[(((1 - s) * 25 + 13 + n) * 12 + cc) * 16 + px], ya);
    }
    yv[cc] = fmaf(u_s, Dv, ya);
  }

  float mu = 0.f;
#pragma unroll
  for (int cc = 0; cc < CCn; ++cc) mu += yv[cc];
  mu *= (1.f / CCn);
  float var = 0.f;
#pragma unroll
  for (int cc = 0; cc < CCn; ++cc) { float t = yv[cc] - mu; var = fmaf(t, t, var); }
  var *= (1.f / CCn);
  float rs = rsqrtf(var + 1e-5f);
  const float* ow = s ? on2w : on1w;
  const float* ob = s ? on2b : on1b;
  __syncthreads();
#pragma unroll
  for (int cc = 0; cc < CCn; ++cc)
    uS[(s * En + d * 12 + cc) * 16 + px] = fmaf((yv[cc] - mu) * rs, ow[cc], ob[cc]);
  __syncthreads();

#pragma unroll
  for (int j = 0; j < 6; ++j) {
    int idx = j * 512 + tid;
    int pxx = idx & 15, ch = (idx >> 4) % 96, ss = idx / 1536;
    int g = ch >> 2, co = ch & 3;
    const float* ow2 = (ss ? opw1 : opw0) + g * 32 + co * 8;
    float a = 0.f;
#pragma unroll
    for (int ci = 0; ci < 8; ++ci)
      a = fmaf(uS[(ss * En + g * 8 + ci) * 16 + pxx], ow2[ci], a);
    a += xr_ws[(((size_t)ss * Bn + b) * Cn + ch) * HWn + l0 + pxx];
    z_ws[(((size_t)ss * Bn + b) * Cn + ch) * HWn + l0 + pxx] = a;
  }
}

// ---------------------------------------------------------------------------
// K4: weight transposes for the fused MLP.
//  w1t[s][c][o] = w1_s[o][c]   (96x384 from 384x96)
//  w2t[s][o][c] = w2_s[c][o]   (384x96 from 96x384)
// ---------------------------------------------------------------------------
__global__ void k_transpose_w(
    const float* __restrict__ w1r, const float* __restrict__ w1e,
    const float* __restrict__ w2r, const float* __restrict__ w2e,
    float* __restrict__ w1t, float* __restrict__ w2t)
{
  int idx = blockIdx.x * 256 + threadIdx.x;     // 0 .. 147455
  int which = idx / 36864;                      // 0:w1r 1:w1e 2:w2r 3:w2e
  int r = idx % 36864;
  if (which < 2) {
    int c = r / HDn, o = r % HDn;               // dest [c][o]
    const float* src = which ? w1e : w1r;       // src [o][c]
    w1t[which * 36864 + r] = src[o * Cn + c];
  } else {
    int o = r / Cn, c = r % Cn;                 // dest [o][c]
    const float* src = (which == 3) ? w2e : w2r; // src [c][o]
    w2t[(which - 2) * 36864 + r] = src[c * HDn + o];
  }
}

// ---------------------------------------------------------------------------
// K5: fused MLP: chanLN(1e-6) + fc1 + GELU(exact) + fc2 + bias + residual.
// grid (1024, 2), 256 threads, 32 pixels per block.
// ---------------------------------------------------------------------------
__global__ __launch_bounds__(256, 2) void k_mlp(
    const float* __restrict__ z_all,
    const float* __restrict__ n1w, const float* __restrict__ n1b,
    const float* __restrict__ n2w, const float* __restrict__ n2b,
    const float* __restrict__ w1t_all, const float* __restrict__ b1r,
    const float* __restrict__ b1e,
    const float* __restrict__ w2t_all, const float* __restrict__ b2r,
    const float* __restrict__ b2e,
    float* __restrict__ out_all)
{
  __shared__ float zn[Cn * 32];        // 12 KB
  __shared__ float hS[HDn * 32];       // 48 KB
  __shared__ float red[2 * 8 * 32];    // 2 KB
  __shared__ float mus[32], rss[32];

  const int s    = blockIdx.y;
  const int tile = blockIdx.x;                 // 0..1023
  const int b    = (tile * 32) >> 14;
  const int l0   = (tile * 32) & (HWn - 1);
  const int tid  = threadIdx.x;

  const float* z   = z_all + ((size_t)s * Bn + b) * Cn * HWn + l0;
  float*       out = (float*)out_all + ((size_t)s * Bn + b) * Cn * HWn + l0;
  const float* nw  = s ? n2w : n1w;
  const float* nb  = s ? n2b : n1b;
  const float* w1t = w1t_all + s * 36864;
  const float* b1  = s ? b1e : b1r;
  const float* w2t = w2t_all + s * 36864;
  const float* b2  = s ? b2e : b2r;

  // ---- phase 0: load z tile + LN ----
  {
    const int px = tid & 31, part = tid >> 5;   // 8 parts x 12 channels
    float psum = 0.f, pss = 0.f;
#pragma unroll
    for (int i = 0; i < 12; ++i) {
      int c = part + 8 * i;
      float v = z[(size_t)c * HWn + px];
      zn[c * 32 + px] = v; psum += v; pss += v * v;
    }
    red[part * 32 + px] = psum;
    red[256 + part * 32 + px] = pss;
    __syncthreads();
    if (tid < 32) {
      float sm = 0.f, sq = 0.f;
#pragma unroll
      for (int p = 0; p < 8; ++p) { sm += red[p * 32 + tid]; sq += red[256 + p * 32 + tid]; }
      float mu = sm * (1.f / Cn);
      float var = sq * (1.f / Cn) - mu * mu;
      mus[tid] = mu; rss[tid] = rsqrtf(var + 1e-6f);
    }
    __syncthreads();
    float mu = mus[px], rs = rss[px];
#pragma unroll
    for (int i = 0; i < 12; ++i) {
      int c = part + 8 * i;
      float v = zn[c * 32 + px];
      zn[c * 32 + px] = fmaf((v - mu) * rs, nw[c], nb[c]);
    }
    __syncthreads();
  }

  const int pg = (tid & 7) << 2;               // pixel base 0,4,...,28

  // ---- phase 1: fc1 + GELU -> hS ----
  {
    const int og = (tid >> 3) * 12;            // output base 0..372
    float acc[12][4];
#pragma unroll
    for (int j = 0; j < 12; ++j)
#pragma unroll
      for (int i = 0; i < 4; ++i) acc[j][i] = 0.f;

    for (int c = 0; c < Cn; ++c) {
      const float* zr = &zn[c * 32 + pg];
      float x0 = zr[0], x1 = zr[1], x2 = zr[2], x3 = zr[3];
      const float* wr = &w1t[c * HDn + og];
#pragma unroll
      for (int j = 0; j < 12; ++j) {
        float w = wr[j];
        acc[j][0] = fmaf(x0, w, acc[j][0]);
        acc[j][1] = fmaf(x1, w, acc[j][1]);
        acc[j][2] = fmaf(x2, w, acc[j][2]);
        acc[j][3] = fmaf(x3, w, acc[j][3]);
      }
    }
#pragma unroll
    for (int j = 0; j < 12; ++j) {
      float bo = b1[og + j];
      float* hr = &hS[(og + j) * 32 + pg];
#pragma unroll
      for (int i = 0; i < 4; ++i) {
        float a = acc[j][i] + bo;
        hr[i] = 0.5f * a * (1.f + erff(a * 0.70710678118654752f));
      }
    }
  }
  __syncthreads();

  // ---- phase 2: fc2 + bias + residual -> out ----
  {
    const int cg = (tid >> 3) * 3;             // out-channel base 0..93
    float a0[4], a1[4], a2[4];
#pragma unroll
    for (int i = 0; i < 4; ++i) { a0[i] = 0.f; a1[i] = 0.f; a2[i] = 0.f; }

    for (int o = 0; o < HDn; ++o) {
      const float* hr = &hS[o * 32 + pg];
      float x0 = hr[0], x1 = hr[1], x2 = hr[2], x3 = hr[3];
      const float* wr = &w2t[o * Cn + cg];
      float w0 = wr[0], w1 = wr[1], w2 = wr[2];
      a0[0] = fmaf(x0, w0, a0[0]); a0[1] = fmaf(x1, w0, a0[1]);
      a0[2] = fmaf(x2, w0, a0[2]); a0[3] = fmaf(x3, w0, a0[3]);
      a1[0] = fmaf(x0, w1, a1[0]); a1[1] = fmaf(x1, w1, a1[1]);
      a1[2] = fmaf(x2, w1, a1[2]); a1[3] = fmaf(x3, w1, a1[3]);
      a2[0] = fmaf(x0, w2, a2[0]); a2[1] = fmaf(x1, w2, a2[1]);
      a2[2] = fmaf(x2, w2, a2[2]); a2[3] = fmaf(x3, w2, a2[3]);
    }
#pragma unroll
    for (int k = 0; k < 3; ++k) {
      int c = cg + k;
      float bk = b2[c];
      const float* ak = (k == 0) ? a0 : (k == 1) ? a1 : a2;
#pragma unroll
      for (int i = 0; i < 4; ++i) {
        size_t off = (size_t)c * HWn + pg + i;
        out[off] = ak[i] + bk + z[off];
      }
    }
  }
}

// ---------------------------------------------------------------------------
extern "C" void kernel_launch(void* const* d_in, const int* in_sizes, int n_in,
                              void* d_out, int out_size, void* d_ws, size_t ws_size,
                              hipStream_t stream)
{
  const float* x_rgb = (const float*)d_in[0];
  const float* x_e   = (const float*)d_in[1];
  const float* in1_w = (const float*)d_in[2];
  const float* in1_b = (const float*)d_in[3];
  const float* in2_w = (const float*)d_in[4];
  const float* in2_b = (const float*)d_in[5];
  const float* ipw0  = (const float*)d_in[6];
  const float* ipw1  = (const float*)d_in[7];
  const float* cw0   = (const float*)d_in[8];
  const float* cb0   = (const float*)d_in[9];
  const float* cw1   = (const float*)d_in[10];
  const float* cb1   = (const float*)d_in[11];
  const float* xprojw  = (const float*)d_in[12];
  const float* dtprojw = (const float*)d_in[13];
  const float* dtprojb = (const float*)d_in[14];
  const float* A_logs  = (const float*)d_in[15];
  const float* Ds      = (const float*)d_in[16];
  const float* on1w  = (const float*)d_in[17];
  const float* on1b  = (const float*)d_in[18];
  const float* on2w  = (const float*)d_in[19];
  const float* on2b  = (const float*)d_in[20];
  const float* opw0  = (const float*)d_in[21];
  const float* opw1  = (const float*)d_in[22];
  const float* n1w   = (const float*)d_in[23];
  const float* n1b   = (const float*)d_in[24];
  const float* n2w   = (const float*)d_in[25];
  const float* n2b   = (const float*)d_in[26];
  const float* w1r   = (const float*)d_in[27];
  const float* b1r   = (const float*)d_in[28];
  const float* w2r   = (const float*)d_in[29];
  const float* b2r   = (const float*)d_in[30];
  const float* w1e   = (const float*)d_in[31];
  const float* b1e   = (const float*)d_in[32];
  const float* w2e   = (const float*)d_in[33];
  const float* b2e   = (const float*)d_in[34];

  float* ws  = (float*)d_ws;
  float* xr  = ws;                              // 2*B*C*HW  = 6291456 f
  float* vz  = ws + (size_t)6291456;            // 2*B*E*HW  = 12582912 f (v, later z)
  float* ut  = ws + (size_t)18874368;           // 2*B*E*HW  = 12582912 f (u; reused for w1t/w2t)
  float* w1t = ut;                              // 2*36864 f (after k_ssm consumed u)
  float* w2t = ut + 73728;                      // 2*36864 f

  dim3 b256(256);

  k_ln_inproj<<<dim3(128, 2), b256, 0, stream>>>(
      x_rgb, x_e, in1_w, in1_b, in2_w, in2_b, ipw0, ipw1, xr, vz);

  k_dwconv_silu<<<dim3(64, En, 4), b256, 0, stream>>>(
      vz, cw0, cb0, cw1, cb1, ut);

  k_ssm<<<dim3(2048), dim3(512), 0, stream>>>(
      ut, xr, vz, xprojw, dtprojw, dtprojb, A_logs, Ds,
      on1w, on1b, on2w, on2b, opw0, opw1);

  // u (in ut) is dead now; reuse its space for the transposed MLP weights.
  k_transpose_w<<<dim3(576), b256, 0, stream>>>(w1r, w1e, w2r, w2e, w1t, w2t);

  k_mlp<<<dim3(1024, 2), b256, 0, stream>>>(
      vz, n1w, n1b, n2w, n2b, w1t, b1r, b1e, w2t, b2r, b2e, (float*)d_out);
}

// Round 6
// 585.851 us; speedup vs baseline: 3.8812x; 1.3326x over previous
//
#include <hip/hip_runtime.h>
#include <math.h>

#define HWn 16384
#define Hn  128
#define Wn  128
#define Bn  2
#define Cn  96
#define En  192
#define Gn  24
#define HEADn 16
#define CCn 12
#define Nn  12
#define HDn 384

// ---------------------------------------------------------------------------
// K1: channel LayerNorm (eps 1e-6) + grouped 1x1 in-projection.
// grid (128, 2): x = pixel tiles over B*L, y = stream (0 rgb, 1 e)
// ---------------------------------------------------------------------------
__global__ __launch_bounds__(256) void k_ln_inproj(
    const float* __restrict__ x0, const float* __restrict__ x1,
    const float* __restrict__ lw0, const float* __restrict__ lb0,
    const float* __restrict__ lw1, const float* __restrict__ lb1,
    const float* __restrict__ pw0, const float* __restrict__ pw1,
    float* __restrict__ xr, float* __restrict__ v)
{
  const int s  = blockIdx.y;
  const int gp = blockIdx.x * 256 + threadIdx.x;   // 0..B*L-1
  const int b  = gp >> 14, l = gp & (HWn - 1);
  const float* x  = s ? x1  : x0;
  const float* lw = s ? lw1 : lw0;
  const float* lb = s ? lb1 : lb0;
  const float* pw = s ? pw1 : pw0;

  float xv[Cn];
  float sum = 0.f, ss = 0.f;
  const float* xp = x + (size_t)b * Cn * HWn + l;
#pragma unroll
  for (int ch = 0; ch < Cn; ++ch) {
    float t = xp[(size_t)ch * HWn];
    xv[ch] = t; sum += t; ss += t * t;
  }
  float mu  = sum * (1.f / Cn);
  float var = ss * (1.f / Cn) - mu * mu;
  float rs  = rsqrtf(var + 1e-6f);

  float* xrp = xr + ((size_t)s * Bn + b) * Cn * HWn + l;
#pragma unroll
  for (int ch = 0; ch < Cn; ++ch) {
    float n = fmaf((xv[ch] - mu) * rs, lw[ch], lb[ch]);
    xv[ch] = n;
    xrp[(size_t)ch * HWn] = n;
  }

  float* vp = v + ((size_t)s * Bn + b) * En * HWn + l;
#pragma unroll
  for (int g = 0; g < Gn; ++g) {
#pragma unroll
    for (int o = 0; o < 8; ++o) {
      float a = 0.f;
#pragma unroll
      for (int i = 0; i < 4; ++i) a = fmaf(xv[g * 4 + i], pw[g * 32 + o * 4 + i], a);
      vp[(size_t)(g * 8 + o) * HWn] = a;
    }
  }
}

// ---------------------------------------------------------------------------
// K2: depthwise 3x3 conv + bias + SiLU. grid (64, 192, 4)
// ---------------------------------------------------------------------------
__global__ __launch_bounds__(256) void k_dwconv_silu(
    const float* __restrict__ v,
    const float* __restrict__ cw0, const float* __restrict__ cb0,
    const float* __restrict__ cw1, const float* __restrict__ cb1,
    float* __restrict__ u)
{
  const int z = blockIdx.z;                 // s*2+b
  const int e = blockIdx.y;
  const int p = blockIdx.x * 256 + threadIdx.x;
  const int h = p >> 7, w = p & 127;
  const int s = z >> 1;
  const float* cw  = (s ? cw1 : cw0) + e * 9;
  const float bias = (s ? cb1 : cb0)[e];
  const float* src = v + ((size_t)z * En + e) * HWn;

  float acc = bias;
#pragma unroll
  for (int kh = 0; kh < 3; ++kh) {
    int hh = h + kh - 1;
    if (hh < 0 || hh >= Hn) continue;
#pragma unroll
    for (int kw = 0; kw < 3; ++kw) {
      int ww = w + kw - 1;
      if (ww < 0 || ww >= Wn) continue;
      acc = fmaf(src[hh * Wn + ww], cw[kh * 3 + kw], acc);
    }
  }
  float sig = 1.f / (1.f + expf(-acc));
  u[((size_t)z * En + e) * HWn + p] = acc * sig;
}

// ---------------------------------------------------------------------------
// K3: SSM core, conflict-free LDS edition. 16 px per block of 512 threads.
//  uS layout:  [px][s][d][13]   px-stride 417, s-stride 208, d-stride 13
//    -> 13d%32 covers 16 distinct banks; +208%32=16 gives the complement;
//       +417%32=1 rotates by one => every access pattern <=2 lanes/bank.
//  xdl layout: [px][s][r][cc12] px-stride 604, s-stride 300, r-stride 12
//    -> cc contiguous: dt/B/C rows read as 3x float4 (broadcast across d).
// ---------------------------------------------------------------------------
#define UPXS 417
#define USS  208
#define UDS  13
#define XPXS 604
#define XSS  300

__global__ __launch_bounds__(512) void k_ssm(
    const float* __restrict__ u_ws, const float* __restrict__ xr_ws,
    float* __restrict__ z_ws,
    const float* __restrict__ xprojw, const float* __restrict__ dtprojw,
    const float* __restrict__ dtprojb, const float* __restrict__ A_logs,
    const float* __restrict__ Ds,
    const float* __restrict__ on1w, const float* __restrict__ on1b,
    const float* __restrict__ on2w, const float* __restrict__ on2b,
    const float* __restrict__ opw0, const float* __restrict__ opw1)
{
  __shared__ __align__(16) float uS[16 * UPXS];    // 6672 f = 26688 B
  __shared__ __align__(16) float xdl[16 * XPXS];   // 9664 f = 38656 B

  const int tid  = threadIdx.x;
  const int tile = blockIdx.x;
  const int b  = (tile * 16) >> 14;
  const int l0 = (tile * 16) & (HWn - 1);

  // ---- hoisted per-(s,d) params for phase 2 (hide latency under staging) ----
  const int p2px = tid >> 5, p2s = (tid >> 4) & 1, p2d = tid & 15;
  const float dtw = dtprojw[p2s * HEADn + p2d];
  const float dtb = dtprojb[p2s * HEADn + p2d];
  const float Dv  = Ds[p2s * HEADn + p2d];
  float Ar[Nn];
  {
    const float4* ap = (const float4*)&A_logs[(p2s * HEADn + p2d) * Nn];
    float4 a0 = ap[0], a1 = ap[1], a2 = ap[2];
    Ar[0]=-expf(a0.x); Ar[1]=-expf(a0.y); Ar[2]=-expf(a0.z); Ar[3]=-expf(a0.w);
    Ar[4]=-expf(a1.x); Ar[5]=-expf(a1.y); Ar[6]=-expf(a1.z); Ar[7]=-expf(a1.w);
    Ar[8]=-expf(a2.x); Ar[9]=-expf(a2.y); Ar[10]=-expf(a2.z); Ar[11]=-expf(a2.w);
  }

  // ---- phase 0: stage u via float4 (1536 f4 = 3*512) ----
#pragma unroll
  for (int i = 0; i < 3; ++i) {
    int id = i * 512 + tid;
    int px4 = id & 3, rest = id >> 2;
    int ch = rest % En, s2 = rest / En;
    float4 t = *(const float4*)&u_ws[(((size_t)s2 * Bn + b) * En + ch) * HWn + l0 + px4 * 4];
    int dd = ch / 12, cc = ch % 12;
    int base = s2 * USS + dd * UDS + cc;
    uS[(px4 * 4 + 0) * UPXS + base] = t.x;
    uS[(px4 * 4 + 1) * UPXS + base] = t.y;
    uS[(px4 * 4 + 2) * UPXS + base] = t.z;
    uS[(px4 * 4 + 3) * UPXS + base] = t.w;
  }
  __syncthreads();

  // ---- phase 1: x_dbl rows. task = (px, s, r), 800 tasks ----
#pragma unroll
  for (int j = 0; j < 2; ++j) {
    int id = j * 512 + tid;
    if (id < 800) {
      int px = id & 15, sr = id >> 4;
      int s2 = sr / 25, r = sr % 25;
      const float4* xw4 = (const float4*)&xprojw[(s2 * 25 + r) * HEADn];
      float4 w0 = xw4[0], w1 = xw4[1], w2 = xw4[2], w3 = xw4[3];
      float wv[16];
      wv[0]=w0.x; wv[1]=w0.y; wv[2]=w0.z; wv[3]=w0.w;
      wv[4]=w1.x; wv[5]=w1.y; wv[6]=w1.z; wv[7]=w1.w;
      wv[8]=w2.x; wv[9]=w2.y; wv[10]=w2.z; wv[11]=w2.w;
      wv[12]=w3.x; wv[13]=w3.y; wv[14]=w3.z; wv[15]=w3.w;
      int ub = px * UPXS + s2 * USS;
      float acc[12];
#pragma unroll
      for (int cc = 0; cc < 12; ++cc) acc[cc] = 0.f;
#pragma unroll
      for (int dd = 0; dd < HEADn; ++dd) {
        float w = wv[dd];
        int ua = ub + dd * UDS;
#pragma unroll
        for (int cc = 0; cc < 12; ++cc)
          acc[cc] = fmaf(uS[ua + cc], w, acc[cc]);
      }
      float* xp = &xdl[px * XPXS + s2 * XSS + r * 12];
      *(float4*)&xp[0] = make_float4(acc[0], acc[1], acc[2], acc[3]);
      *(float4*)&xp[4] = make_float4(acc[4], acc[5], acc[6], acc[7]);
      *(float4*)&xp[8] = make_float4(acc[8], acc[9], acc[10], acc[11]);
    }
  }
  __syncthreads();

  // ---- phase 2: scan. thread = (px, s, d) ----
  {
    const int px = p2px, s = p2s, d = p2d;
    const int ub = px * UPXS + s * USS + d * UDS;
    float uvv[12];
#pragma unroll
    for (int cc = 0; cc < 12; ++cc) uvv[cc] = uS[ub + cc];

    const int xb = px * XPXS;
    float dts[12];
    {
      const float4* dr = (const float4*)&xdl[xb + s * XSS];   // r = 0
      float4 q0 = dr[0], q1 = dr[1], q2 = dr[2];
      dts[0]=q0.x; dts[1]=q0.y; dts[2]=q0.z; dts[3]=q0.w;
      dts[4]=q1.x; dts[5]=q1.y; dts[6]=q1.z; dts[7]=q1.w;
      dts[8]=q2.x; dts[9]=q2.y; dts[10]=q2.z; dts[11]=q2.w;
    }
    float dt_s[12], dtu[12];
#pragma unroll
    for (int cc = 0; cc < 12; ++cc) {
      float pre = fmaf(dts[cc], dtw, dtb);
      float v = (pre > 20.f) ? pre : log1pf(expf(pre));       // softplus
      dt_s[cc] = v;
      dtu[cc] = v * uvv[cc];
    }

    float y[12];
#pragma unroll
    for (int cc = 0; cc < 12; ++cc) y[cc] = 0.f;

#pragma unroll
    for (int n = 0; n < Nn; ++n) {
      const float4* Br = (const float4*)&xdl[xb + s * XSS + (1 + n) * 12];
      const float4* Cr = (const float4*)&xdl[xb + (1 - s) * XSS + (13 + n) * 12];
      float4 b0 = Br[0], b1 = Br[1], b2 = Br[2];
      float4 c0 = Cr[0], c1 = Cr[1], c2 = Cr[2];
      float Bv[12], Cv[12];
      Bv[0]=b0.x; Bv[1]=b0.y; Bv[2]=b0.z; Bv[3]=b0.w;
      Bv[4]=b1.x; Bv[5]=b1.y; Bv[6]=b1.z; Bv[7]=b1.w;
      Bv[8]=b2.x; Bv[9]=b2.y; Bv[10]=b2.z; Bv[11]=b2.w;
      Cv[0]=c0.x; Cv[1]=c0.y; Cv[2]=c0.z; Cv[3]=c0.w;
      Cv[4]=c1.x; Cv[5]=c1.y; Cv[6]=c1.z; Cv[7]=c1.w;
      Cv[8]=c2.x; Cv[9]=c2.y; Cv[10]=c2.z; Cv[11]=c2.w;
      float h = 0.f;
      float An = Ar[n];
#pragma unroll
      for (int cc = 0; cc < 12; ++cc) {
        float dA = expf(dt_s[cc] * An);
        h = fmaf(dA, h, dtu[cc] * Bv[cc]);
        y[cc] = fmaf(h, Cv[cc], y[cc]);
      }
    }

#pragma unroll
    for (int cc = 0; cc < 12; ++cc) y[cc] = fmaf(uvv[cc], Dv, y[cc]);

    // LayerNorm over cc, eps 1e-5
    float mu = 0.f;
#pragma unroll
    for (int cc = 0; cc < 12; ++cc) mu += y[cc];
    mu *= (1.f / CCn);
    float var = 0.f;
#pragma unroll
    for (int cc = 0; cc < 12; ++cc) { float t = y[cc] - mu; var = fmaf(t, t, var); }
    var *= (1.f / CCn);
    float rs = rsqrtf(var + 1e-5f);
    const float* ow = s ? on2w : on1w;
    const float* ob = s ? on2b : on1b;
    // write yn in place (each thread owns its own [px][s][d][*] slots)
#pragma unroll
    for (int cc = 0; cc < 12; ++cc)
      uS[ub + cc] = fmaf((y[cc] - mu) * rs, ow[cc], ob[cc]);
  }
  __syncthreads();

  // ---- phase 3: grouped outproj + residual, float4 I/O. 768 f4 outputs ----
#pragma unroll
  for (int i = 0; i < 2; ++i) {
    int id = i * 512 + tid;
    if (id < 768) {
      int px4 = id & 3, ch = (id >> 2) % Cn, ss = id / 384;
      int g = ch >> 2, co = ch & 3;
      const float* ow2 = (ss ? opw1 : opw0) + g * 32 + co * 8;
      float a0 = 0.f, a1 = 0.f, a2 = 0.f, a3 = 0.f;
#pragma unroll
      for (int ci = 0; ci < 8; ++ci) {
        int e = g * 8 + ci;
        int dd = e / 12, cc = e % 12;
        int base = ss * USS + dd * UDS + cc;
        float w = ow2[ci];
        a0 = fmaf(uS[(px4 * 4 + 0) * UPXS + base], w, a0);
        a1 = fmaf(uS[(px4 * 4 + 1) * UPXS + base], w, a1);
        a2 = fmaf(uS[(px4 * 4 + 2) * UPXS + base], w, a2);
        a3 = fmaf(uS[(px4 * 4 + 3) * UPXS + base], w, a3);
      }
      size_t go = (((size_t)ss * Bn + b) * Cn + ch) * HWn + l0 + px4 * 4;
      float4 xrv = *(const float4*)&xr_ws[go];
      *(float4*)&z_ws[go] =
          make_float4(a0 + xrv.x, a1 + xrv.y, a2 + xrv.z, a3 + xrv.w);
    }
  }
}

// ---------------------------------------------------------------------------
// K4: weight transposes for the fused MLP.
// ---------------------------------------------------------------------------
__global__ void k_transpose_w(
    const float* __restrict__ w1r, const float* __restrict__ w1e,
    const float* __restrict__ w2r, const float* __restrict__ w2e,
    float* __restrict__ w1t, float* __restrict__ w2t)
{
  int idx = blockIdx.x * 256 + threadIdx.x;     // 0 .. 147455
  int which = idx / 36864;                      // 0:w1r 1:w1e 2:w2r 3:w2e
  int r = idx % 36864;
  if (which < 2) {
    int c = r / HDn, o = r % HDn;               // dest [c][o]
    const float* src = which ? w1e : w1r;       // src [o][c]
    w1t[which * 36864 + r] = src[o * Cn + c];
  } else {
    int o = r / Cn, c = r % Cn;                 // dest [o][c]
    const float* src = (which == 3) ? w2e : w2r; // src [c][o]
    w2t[(which - 2) * 36864 + r] = src[c * HDn + o];
  }
}

// ---------------------------------------------------------------------------
// K5: fused MLP: chanLN(1e-6) + fc1 + GELU(exact) + fc2 + bias + residual.
// grid (1024, 2), 256 threads, 32 pixels per block.
// ---------------------------------------------------------------------------
__global__ __launch_bounds__(256, 2) void k_mlp(
    const float* __restrict__ z_all,
    const float* __restrict__ n1w, const float* __restrict__ n1b,
    const float* __restrict__ n2w, const float* __restrict__ n2b,
    const float* __restrict__ w1t_all, const float* __restrict__ b1r,
    const float* __restrict__ b1e,
    const float* __restrict__ w2t_all, const float* __restrict__ b2r,
    const float* __restrict__ b2e,
    float* __restrict__ out_all)
{
  __shared__ float zn[Cn * 32];        // 12 KB
  __shared__ float hS[HDn * 32];       // 48 KB
  __shared__ float red[2 * 8 * 32];    // 2 KB
  __shared__ float mus[32], rss[32];

  const int s    = blockIdx.y;
  const int tile = blockIdx.x;                 // 0..1023
  const int b    = (tile * 32) >> 14;
  const int l0   = (tile * 32) & (HWn - 1);
  const int tid  = threadIdx.x;

  const float* z   = z_all + ((size_t)s * Bn + b) * Cn * HWn + l0;
  float*       out = (float*)out_all + ((size_t)s * Bn + b) * Cn * HWn + l0;
  const float* nw  = s ? n2w : n1w;
  const float* nb  = s ? n2b : n1b;
  const float* w1t = w1t_all + s * 36864;
  const float* b1  = s ? b1e : b1r;
  const float* w2t = w2t_all + s * 36864;
  const float* b2  = s ? b2e : b2r;

  // ---- phase 0: load z tile + LN ----
  {
    const int px = tid & 31, part = tid >> 5;   // 8 parts x 12 channels
    float psum = 0.f, pss = 0.f;
#pragma unroll
    for (int i = 0; i < 12; ++i) {
      int c = part + 8 * i;
      float v = z[(size_t)c * HWn + px];
      zn[c * 32 + px] = v; psum += v; pss += v * v;
    }
    red[part * 32 + px] = psum;
    red[256 + part * 32 + px] = pss;
    __syncthreads();
    if (tid < 32) {
      float sm = 0.f, sq = 0.f;
#pragma unroll
      for (int p = 0; p < 8; ++p) { sm += red[p * 32 + tid]; sq += red[256 + p * 32 + tid]; }
      float mu = sm * (1.f / Cn);
      float var = sq * (1.f / Cn) - mu * mu;
      mus[tid] = mu; rss[tid] = rsqrtf(var + 1e-6f);
    }
    __syncthreads();
    float mu = mus[px], rs = rss[px];
#pragma unroll
    for (int i = 0; i < 12; ++i) {
      int c = part + 8 * i;
      float v = zn[c * 32 + px];
      zn[c * 32 + px] = fmaf((v - mu) * rs, nw[c], nb[c]);
    }
    __syncthreads();
  }

  const int pg = (tid & 7) << 2;               // pixel base 0,4,...,28

  // ---- phase 1: fc1 + GELU -> hS ----
  {
    const int og = (tid >> 3) * 12;            // output base 0..372
    float acc[12][4];
#pragma unroll
    for (int j = 0; j < 12; ++j)
#pragma unroll
      for (int i = 0; i < 4; ++i) acc[j][i] = 0.f;

    for (int c = 0; c < Cn; ++c) {
      const float* zr = &zn[c * 32 + pg];
      float x0 = zr[0], x1 = zr[1], x2 = zr[2], x3 = zr[3];
      const float* wr = &w1t[c * HDn + og];
#pragma unroll
      for (int j = 0; j < 12; ++j) {
        float w = wr[j];
        acc[j][0] = fmaf(x0, w, acc[j][0]);
        acc[j][1] = fmaf(x1, w, acc[j][1]);
        acc[j][2] = fmaf(x2, w, acc[j][2]);
        acc[j][3] = fmaf(x3, w, acc[j][3]);
      }
    }
#pragma unroll
    for (int j = 0; j < 12; ++j) {
      float bo = b1[og + j];
      float* hr = &hS[(og + j) * 32 + pg];
#pragma unroll
      for (int i = 0; i < 4; ++i) {
        float a = acc[j][i] + bo;
        hr[i] = 0.5f * a * (1.f + erff(a * 0.70710678118654752f));
      }
    }
  }
  __syncthreads();

  // ---- phase 2: fc2 + bias + residual -> out ----
  {
    const int cg = (tid >> 3) * 3;             // out-channel base 0..93
    float a0[4], a1[4], a2[4];
#pragma unroll
    for (int i = 0; i < 4; ++i) { a0[i] = 0.f; a1[i] = 0.f; a2[i] = 0.f; }

    for (int o = 0; o < HDn; ++o) {
      const float* hr = &hS[o * 32 + pg];
      float x0 = hr[0], x1 = hr[1], x2 = hr[2], x3 = hr[3];
      const float* wr = &w2t[o * Cn + cg];
      float w0 = wr[0], w1 = wr[1], w2 = wr[2];
      a0[0] = fmaf(x0, w0, a0[0]); a0[1] = fmaf(x1, w0, a0[1]);
      a0[2] = fmaf(x2, w0, a0[2]); a0[3] = fmaf(x3, w0, a0[3]);
      a1[0] = fmaf(x0, w1, a1[0]); a1[1] = fmaf(x1, w1, a1[1]);
      a1[2] = fmaf(x2, w1, a1[2]); a1[3] = fmaf(x3, w1, a1[3]);
      a2[0] = fmaf(x0, w2, a2[0]); a2[1] = fmaf(x1, w2, a2[1]);
      a2[2] = fmaf(x2, w2, a2[2]); a2[3] = fmaf(x3, w2, a2[3]);
    }
#pragma unroll
    for (int k = 0; k < 3; ++k) {
      int c = cg + k;
      float bk = b2[c];
      const float* ak = (k == 0) ? a0 : (k == 1) ? a1 : a2;
#pragma unroll
      for (int i = 0; i < 4; ++i) {
        size_t off = (size_t)c * HWn + pg + i;
        out[off] = ak[i] + bk + z[off];
      }
    }
  }
}

// ---------------------------------------------------------------------------
extern "C" void kernel_launch(void* const* d_in, const int* in_sizes, int n_in,
                              void* d_out, int out_size, void* d_ws, size_t ws_size,
                              hipStream_t stream)
{
  const float* x_rgb = (const float*)d_in[0];
  const float* x_e   = (const float*)d_in[1];
  const float* in1_w = (const float*)d_in[2];
  const float* in1_b = (const float*)d_in[3];
  const float* in2_w = (const float*)d_in[4];
  const float* in2_b = (const float*)d_in[5];
  const float* ipw0  = (const float*)d_in[6];
  const float* ipw1  = (const float*)d_in[7];
  const float* cw0   = (const float*)d_in[8];
  const float* cb0   = (const float*)d_in[9];
  const float* cw1   = (const float*)d_in[10];
  const float* cb1   = (const float*)d_in[11];
  const float* xprojw  = (const float*)d_in[12];
  const float* dtprojw = (const float*)d_in[13];
  const float* dtprojb = (const float*)d_in[14];
  const float* A_logs  = (const float*)d_in[15];
  const float* Ds      = (const float*)d_in[16];
  const float* on1w  = (const float*)d_in[17];
  const float* on1b  = (const float*)d_in[18];
  const float* on2w  = (const float*)d_in[19];
  const float* on2b  = (const float*)d_in[20];
  const float* opw0  = (const float*)d_in[21];
  const float* opw1  = (const float*)d_in[22];
  const float* n1w   = (const float*)d_in[23];
  const float* n1b   = (const float*)d_in[24];
  const float* n2w   = (const float*)d_in[25];
  const float* n2b   = (const float*)d_in[26];
  const float* w1r   = (const float*)d_in[27];
  const float* b1r   = (const float*)d_in[28];
  const float* w2r   = (const float*)d_in[29];
  const float* b2r   = (const float*)d_in[30];
  const float* w1e   = (const float*)d_in[31];
  const float* b1e   = (const float*)d_in[32];
  const float* w2e   = (const float*)d_in[33];
  const float* b2e   = (const float*)d_in[34];

  float* ws  = (float*)d_ws;
  float* xr  = ws;                              // 2*B*C*HW  = 6291456 f
  float* vz  = ws + (size_t)6291456;            // 2*B*E*HW  = 12582912 f (v, later z)
  float* ut  = ws + (size_t)18874368;           // 2*B*E*HW  = 12582912 f (u; reused for w1t/w2t)
  float* w1t = ut;                              // 2*36864 f (after k_ssm consumed u)
  float* w2t = ut + 73728;                      // 2*36864 f

  dim3 b256(256);

  k_ln_inproj<<<dim3(128, 2), b256, 0, stream>>>(
      x_rgb, x_e, in1_w, in1_b, in2_w, in2_b, ipw0, ipw1, xr, vz);

  k_dwconv_silu<<<dim3(64, En, 4), b256, 0, stream>>>(
      vz, cw0, cb0, cw1, cb1, ut);

  k_ssm<<<dim3(2048), dim3(512), 0, stream>>>(
      ut, xr, vz, xprojw, dtprojw, dtprojb, A_logs, Ds,
      on1w, on1b, on2w, on2b, opw0, opw1);

  // u (in ut) is dead now; reuse its space for the transposed MLP weights.
  k_transpose_w<<<dim3(576), b256, 0, stream>>>(w1r, w1e, w2r, w2e, w1t, w2t);

  k_mlp<<<dim3(1024, 2), b256, 0, stream>>>(
      vz, n1w, n1b, n2w, n2b, w1t, b1r, b1e, w2t, b2r, b2e, (float*)d_out);
}